// Round 1
// baseline (503.623 us; speedup 1.0000x reference)
//
#include <hip/hip_runtime.h>
#include <hip/hip_bf16.h>

typedef __bf16 bf16x8 __attribute__((ext_vector_type(8)));
typedef float f32x4 __attribute__((ext_vector_type(4)));
typedef unsigned short u16;

#define S_ 2048
#define D_ 2048
#define H_ 16
#define HD_ 128
#define SCALE_ 0.08838834764831845f   // 1/sqrt(128)

__device__ __forceinline__ u16 f2bf(float f) {
  unsigned u = __builtin_bit_cast(unsigned, f);
  u += 0x7fffu + ((u >> 16) & 1u);    // RNE
  return (u16)(u >> 16);
}

__device__ __forceinline__ void gload16(void* lds, const void* g) {
  __builtin_amdgcn_global_load_lds((const __attribute__((address_space(1))) void*)g,
                                   (__attribute__((address_space(3))) void*)lds, 16, 0, 0);
}

__device__ __forceinline__ f32x4 mfma16(bf16x8 a, bf16x8 b, f32x4 c) {
  return __builtin_amdgcn_mfma_f32_16x16x32_bf16(a, b, c, 0, 0, 0);
}

// ---------------- cast f32 -> bf16, vectorized ----------------
__global__ void k_cast_bf16(const float* __restrict__ in, u16* __restrict__ out, int n4) {
  int i = blockIdx.x * blockDim.x + threadIdx.x;
  if (i < n4) {
    float4 v = ((const float4*)in)[i];
    ushort4 o;
    o.x = f2bf(v.x); o.y = f2bf(v.y); o.z = f2bf(v.z); o.w = f2bf(v.w);
    ((ushort4*)out)[i] = o;
  }
}

// ------------- transpose + cast: in[rows][cols] f32 -> out[cols][rows] bf16 -------------
__global__ void k_transpose_cast(const float* __restrict__ in, u16* __restrict__ out,
                                 int rows, int cols) {
  __shared__ u16 tile[32][33];
  int c0 = blockIdx.x * 32, r0 = blockIdx.y * 32;
  int tx = threadIdx.x, ty = threadIdx.y;   // (32,8)
#pragma unroll
  for (int i = 0; i < 4; i++) {
    int r = r0 + ty + i * 8;
    tile[ty + i * 8][tx] = f2bf(in[(long)r * cols + c0 + tx]);
  }
  __syncthreads();
#pragma unroll
  for (int i = 0; i < 4; i++) {
    int c = c0 + ty + i * 8;
    out[(long)c * rows + r0 + tx] = tile[tx][ty + i * 8];
  }
}

// ------------- extract V^T: qkv[4096][6144] -> vt[32][128][2048] -------------
__global__ void k_extract_vt(const u16* __restrict__ qkv, u16* __restrict__ vt) {
  __shared__ u16 tile[32][33];
  int bh = blockIdx.z, b = bh >> 4, h = bh & 15;
  int d0 = blockIdx.x * 32, s0 = blockIdx.y * 32;
  int tx = threadIdx.x, ty = threadIdx.y;
#pragma unroll
  for (int i = 0; i < 4; i++) {
    int s = s0 + ty + i * 8;
    tile[ty + i * 8][tx] = qkv[(long)(b * S_ + s) * 6144 + h * 384 + 256 + d0 + tx];
  }
  __syncthreads();
#pragma unroll
  for (int i = 0; i < 4; i++) {
    int d = d0 + ty + i * 8;
    vt[((long)bh * HD_ + d) * S_ + s0 + tx] = tile[tx][ty + i * 8];
  }
}

// ------------- GEMM: C[M][N] = A[M][K] * Bt[N][K]^T + bias, A/Bt bf16, acc f32 -------------
// 128x128 tile, 4 waves (2x2 of 64x64), BK=32, global_load_lds staging, XOR-swizzled LDS.
template <bool BF16OUT>
__global__ __launch_bounds__(256) void k_gemm_bt(const u16* __restrict__ A,
                                                 const u16* __restrict__ Bt,
                                                 const float* __restrict__ bias,
                                                 void* __restrict__ Cv,
                                                 int M, int N, int K) {
  __shared__ u16 lA[128 * 32];
  __shared__ u16 lB[128 * 32];
  const int tid = threadIdx.x;
  const int w = tid >> 6, l = tid & 63;
  const int wr = w >> 1, wc = w & 1;
  const int lr = l & 15, lg = l >> 4;
  const int tm = blockIdx.y * 128, tn = blockIdx.x * 128;
  const int Rr = l >> 2, Pp = l & 3;

  f32x4 acc[4][4];
#pragma unroll
  for (int m = 0; m < 4; m++)
#pragma unroll
    for (int n = 0; n < 4; n++) acc[m][n] = {0.f, 0.f, 0.f, 0.f};

  for (int k0 = 0; k0 < K; k0 += 32) {
#pragma unroll
    for (int i = 0; i < 2; i++) {
      int R = (i * 4 + w) * 16 + Rr;
      int cg = Pp ^ (R & 3);
      gload16(&lA[(i * 4 + w) * 512], &A[(long)(tm + R) * K + k0 + cg * 8]);
    }
#pragma unroll
    for (int i = 0; i < 2; i++) {
      int R = (i * 4 + w) * 16 + Rr;
      int cg = Pp ^ (R & 3);
      gload16(&lB[(i * 4 + w) * 512], &Bt[(long)(tn + R) * K + k0 + cg * 8]);
    }
    __syncthreads();
    bf16x8 af[4], bfr[4];
#pragma unroll
    for (int m = 0; m < 4; m++) {
      int r = wr * 64 + m * 16 + lr;
      af[m] = *(const bf16x8*)&lA[r * 32 + ((lg ^ (r & 3)) << 3)];
    }
#pragma unroll
    for (int n = 0; n < 4; n++) {
      int r = wc * 64 + n * 16 + lr;
      bfr[n] = *(const bf16x8*)&lB[r * 32 + ((lg ^ (r & 3)) << 3)];
    }
#pragma unroll
    for (int m = 0; m < 4; m++)
#pragma unroll
      for (int n = 0; n < 4; n++) acc[m][n] = mfma16(af[m], bfr[n], acc[m][n]);
    __syncthreads();
  }

#pragma unroll
  for (int n = 0; n < 4; n++) {
    int col = tn + wc * 64 + n * 16 + lr;
    float bv = bias[col];
#pragma unroll
    for (int m = 0; m < 4; m++) {
      int row0 = tm + wr * 64 + m * 16 + lg * 4;
#pragma unroll
      for (int j = 0; j < 4; j++) {
        float v = acc[m][n][j] + bv;
        if constexpr (BF16OUT)
          ((u16*)Cv)[(long)(row0 + j) * N + col] = f2bf(v);
        else
          ((float*)Cv)[(long)(row0 + j) * N + col] = v;
      }
    }
  }
}

// ------------- causal flash attention -------------
// grid (qt=16, bh=32), 256 thr = 4 waves, each wave owns 32 q-rows. KV tiles of 64.
__global__ __launch_bounds__(256) void k_attn(const u16* __restrict__ qkv,
                                              const u16* __restrict__ vt,
                                              const float* __restrict__ amask,
                                              u16* __restrict__ ctx) {
  __shared__ u16 lK[64 * 128];    // [key][d], chunk^(key&7) swizzle
  __shared__ u16 lV[128 * 64];    // [d][key], chunk^(d&7) swizzle
  __shared__ u16 lP[4][32 * 64];  // per-wave [qrow][key], chunk^(row&7) swizzle
  const int qt = blockIdx.x;
  const int bh = blockIdx.y, b = bh >> 4, h = bh & 15;
  const int tid = threadIdx.x, w = tid >> 6, l = tid & 63;
  const int lr = l & 15, lg = l >> 4;
  const int qrow0 = qt * 128 + w * 32;

  // Q fragments held in registers (direct global loads, 16B aligned)
  bf16x8 qf[2][4];
#pragma unroll
  for (int m = 0; m < 2; m++)
#pragma unroll
    for (int ks = 0; ks < 4; ks++)
      qf[m][ks] = *(const bf16x8*)&qkv[(long)(b * S_ + qrow0 + m * 16 + lr) * 6144 +
                                       h * 384 + ks * 32 + lg * 8];

  f32x4 accO[2][8];
#pragma unroll
  for (int m = 0; m < 2; m++)
#pragma unroll
    for (int n = 0; n < 8; n++) accO[m][n] = {0.f, 0.f, 0.f, 0.f};
  float mrun[2][4], lrun[2][4];
#pragma unroll
  for (int m = 0; m < 2; m++)
#pragma unroll
    for (int j = 0; j < 4; j++) { mrun[m][j] = -3.0e38f; lrun[m][j] = 0.f; }

  const int ntiles = 2 * qt + 2;
  for (int t = 0; t < ntiles; ++t) {
    // stage K tile [64][128]: 1024 16B chunks, source pre-swizzled
#pragma unroll
    for (int i = 0; i < 4; i++) {
      int base = i * 256 + w * 64;             // wave-uniform chunk base
      int f = base + l;
      int r = f >> 4, cg = (f & 15) ^ (r & 7);
      gload16(&lK[base * 8],
              &qkv[(long)(b * S_ + t * 64 + r) * 6144 + h * 384 + 128 + cg * 8]);
    }
    // stage Vt tile [128][64]
#pragma unroll
    for (int i = 0; i < 4; i++) {
      int base = i * 256 + w * 64;
      int f = base + l;
      int r = f >> 3, cg = (f & 7) ^ (r & 7);
      gload16(&lV[base * 8], &vt[((long)bh * HD_ + r) * S_ + t * 64 + cg * 8]);
    }
    __syncthreads();

    const bool active = (t * 64 <= qrow0 + 31);
    if (active) {
      // QK^T
      f32x4 accS[2][4];
#pragma unroll
      for (int m = 0; m < 2; m++)
#pragma unroll
        for (int n = 0; n < 4; n++) accS[m][n] = {0.f, 0.f, 0.f, 0.f};
#pragma unroll
      for (int ks = 0; ks < 4; ks++) {
        bf16x8 kf[4];
#pragma unroll
        for (int n = 0; n < 4; n++) {
          int key = n * 16 + lr;
          kf[n] = *(const bf16x8*)&lK[key * 128 + (((ks * 4 + lg) ^ (key & 7)) << 3)];
        }
#pragma unroll
        for (int m = 0; m < 2; m++)
#pragma unroll
          for (int n = 0; n < 4; n++) accS[m][n] = mfma16(qf[m][ks], kf[n], accS[m][n]);
      }
      float am[4];
#pragma unroll
      for (int n = 0; n < 4; n++) am[n] = amask[b * S_ + t * 64 + n * 16 + lr];
      const bool needmask = (t * 64 + 63 > qrow0);
      // online softmax per owned row (m,j); row replicated across the 16-lane group
#pragma unroll
      for (int m = 0; m < 2; m++) {
#pragma unroll
        for (int j = 0; j < 4; j++) {
          const int row = qrow0 + m * 16 + lg * 4 + j;
          const int prow = m * 16 + lg * 4 + j;
          float v[4];
#pragma unroll
          for (int n = 0; n < 4; n++) {
            v[n] = accS[m][n][j] * SCALE_ + am[n];
            if (needmask && (t * 64 + n * 16 + lr) > row) v[n] = -1e30f;
          }
          float rmax = fmaxf(fmaxf(v[0], v[1]), fmaxf(v[2], v[3]));
#pragma unroll
          for (int o = 1; o < 16; o <<= 1) rmax = fmaxf(rmax, __shfl_xor(rmax, o));
          const float mnew = fmaxf(mrun[m][j], rmax);
          const float corr = __expf(mrun[m][j] - mnew);
          float ls = 0.f;
#pragma unroll
          for (int n = 0; n < 4; n++) {
            float p = __expf(v[n] - mnew);
            ls += p;
            int pcol = n * 16 + lr;
            lP[w][prow * 64 + ((((pcol >> 3) ^ (prow & 7)) << 3) | (pcol & 7))] = f2bf(p);
          }
#pragma unroll
          for (int o = 1; o < 16; o <<= 1) ls += __shfl_xor(ls, o);
          lrun[m][j] = lrun[m][j] * corr + ls;
          mrun[m][j] = mnew;
#pragma unroll
          for (int n = 0; n < 8; n++) accO[m][n][j] *= corr;
        }
      }
      // PV: O += P * V   (A = P from wave-private LDS, B^T = Vt)
#pragma unroll
      for (int ks = 0; ks < 2; ks++) {
        bf16x8 pa[2];
#pragma unroll
        for (int m = 0; m < 2; m++) {
          int r = m * 16 + lr;
          pa[m] = *(const bf16x8*)&lP[w][r * 64 + (((ks * 4 + lg) ^ (r & 7)) << 3)];
        }
#pragma unroll
        for (int n = 0; n < 8; n++) {
          int d = n * 16 + lr;
          bf16x8 vb = *(const bf16x8*)&lV[d * 64 + (((ks * 4 + lg) ^ (d & 7)) << 3)];
#pragma unroll
          for (int m = 0; m < 2; m++) accO[m][n] = mfma16(pa[m], vb, accO[m][n]);
        }
      }
    }
    __syncthreads();
  }

  // epilogue: O /= l, write ctx[b,s, h*128 + d] bf16
#pragma unroll
  for (int m = 0; m < 2; m++) {
#pragma unroll
    for (int j = 0; j < 4; j++) {
      float inv = 1.0f / lrun[m][j];
      int srow = qrow0 + m * 16 + lg * 4 + j;
#pragma unroll
      for (int n = 0; n < 8; n++)
        ctx[(long)(b * S_ + srow) * D_ + h * HD_ + n * 16 + lr] = f2bf(accO[m][n][j] * inv);
    }
  }
}

extern "C" void kernel_launch(void* const* d_in, const int* in_sizes, int n_in,
                              void* d_out, int out_size, void* d_ws, size_t ws_size,
                              hipStream_t stream) {
  const float* x  = (const float*)d_in[0];
  const float* am = (const float*)d_in[1];
  const float* wq = (const float*)d_in[2];
  const float* bq = (const float*)d_in[3];
  const float* wd = (const float*)d_in[4];
  const float* bd = (const float*)d_in[5];
  float* out = (float*)d_out;
  char* ws = (char*)d_ws;

  // workspace layout (92.3 MB peak, overlaid):
  u16* xb   = (u16*)(ws);                          // [4096][2048] bf16, 16 MB
  u16* wqT  = (u16*)(ws + (size_t)16777216);       // [6144][2048] bf16, 24 MB
  u16* qkvb = (u16*)(ws + (size_t)41943040);       // [4096][6144] bf16, 48 MB
  u16* vtb  = (u16*)(ws + (size_t)16777216);       // [32][128][2048] bf16 (reuses wqT)
  u16* wdT  = (u16*)(ws + (size_t)33554432);       // [2048][2048] bf16 (reuses wqT tail)
  u16* ctxb = (u16*)(ws);                          // [4096][2048] bf16 (reuses xb)

  k_cast_bf16<<<8192, 256, 0, stream>>>(x, xb, 2097152);
  k_transpose_cast<<<dim3(192, 64), dim3(32, 8), 0, stream>>>(wq, wqT, 2048, 6144);
  k_gemm_bt<true><<<dim3(48, 32), 256, 0, stream>>>(xb, wqT, bq, (void*)qkvb, 4096, 6144, 2048);
  k_extract_vt<<<dim3(4, 64, 32), dim3(32, 8), 0, stream>>>(qkvb, vtb);
  k_transpose_cast<<<dim3(64, 64), dim3(32, 8), 0, stream>>>(wd, wdT, 2048, 2048);
  k_attn<<<dim3(16, 32), 256, 0, stream>>>(qkvb, vtb, am, ctxb);
  k_gemm_bt<false><<<dim3(16, 32), 256, 0, stream>>>(ctxb, wdT, bd, (void*)out, 4096, 2048, 2048);
}

// Round 2
// 392.129 us; speedup vs baseline: 1.2843x; 1.2843x over previous
//
#include <hip/hip_runtime.h>
#include <hip/hip_bf16.h>

typedef __bf16 bf16x8 __attribute__((ext_vector_type(8)));
typedef float f32x4 __attribute__((ext_vector_type(4)));
typedef unsigned short u16;

#define S_ 2048
#define D_ 2048
#define H_ 16
#define HD_ 128
#define SCALE_ 0.08838834764831845f   // 1/sqrt(128)

__device__ __forceinline__ u16 f2bf(float f) {
  unsigned u = __builtin_bit_cast(unsigned, f);
  u += 0x7fffu + ((u >> 16) & 1u);    // RNE
  return (u16)(u >> 16);
}

__device__ __forceinline__ void gload16(void* lds, const void* g) {
  __builtin_amdgcn_global_load_lds((const __attribute__((address_space(1))) void*)g,
                                   (__attribute__((address_space(3))) void*)lds, 16, 0, 0);
}

__device__ __forceinline__ f32x4 mfma16(bf16x8 a, bf16x8 b, f32x4 c) {
  return __builtin_amdgcn_mfma_f32_16x16x32_bf16(a, b, c, 0, 0, 0);
}

// ---------------- cast f32 -> bf16, vectorized ----------------
__global__ void k_cast_bf16(const float* __restrict__ in, u16* __restrict__ out, int n4) {
  int i = blockIdx.x * blockDim.x + threadIdx.x;
  if (i < n4) {
    float4 v = ((const float4*)in)[i];
    ushort4 o;
    o.x = f2bf(v.x); o.y = f2bf(v.y); o.z = f2bf(v.z); o.w = f2bf(v.w);
    ((ushort4*)out)[i] = o;
  }
}

// ------------- transpose + cast: in[rows][cols] f32 -> out[cols][rows] bf16 -------------
__global__ void k_transpose_cast(const float* __restrict__ in, u16* __restrict__ out,
                                 int rows, int cols) {
  __shared__ u16 tile[32][33];
  int c0 = blockIdx.x * 32, r0 = blockIdx.y * 32;
  int tx = threadIdx.x, ty = threadIdx.y;   // (32,8)
#pragma unroll
  for (int i = 0; i < 4; i++) {
    int r = r0 + ty + i * 8;
    tile[ty + i * 8][tx] = f2bf(in[(long)r * cols + c0 + tx]);
  }
  __syncthreads();
#pragma unroll
  for (int i = 0; i < 4; i++) {
    int c = c0 + ty + i * 8;
    out[(long)c * rows + r0 + tx] = tile[tx][ty + i * 8];
  }
}

// ------------- extract V^T: qkv[4096][6144] -> vt[32][128][2048] -------------
__global__ void k_extract_vt(const u16* __restrict__ qkv, u16* __restrict__ vt) {
  __shared__ u16 tile[32][33];
  int bh = blockIdx.z, b = bh >> 4, h = bh & 15;
  int d0 = blockIdx.x * 32, s0 = blockIdx.y * 32;
  int tx = threadIdx.x, ty = threadIdx.y;
#pragma unroll
  for (int i = 0; i < 4; i++) {
    int s = s0 + ty + i * 8;
    tile[ty + i * 8][tx] = qkv[(long)(b * S_ + s) * 6144 + h * 384 + 256 + d0 + tx];
  }
  __syncthreads();
#pragma unroll
  for (int i = 0; i < 4; i++) {
    int d = d0 + ty + i * 8;
    vt[((long)bh * HD_ + d) * S_ + s0 + tx] = tile[tx][ty + i * 8];
  }
}

// ------------- GEMM: C[M][N] = A[M][K] * Bt[N][K]^T + bias, A/Bt bf16, acc f32 -------------
// 128x128 tile, 4 waves (2x2 of 64x64), BK=32, global_load_lds staging, XOR-swizzled LDS.
template <bool BF16OUT>
__global__ __launch_bounds__(256) void k_gemm_bt(const u16* __restrict__ A,
                                                 const u16* __restrict__ Bt,
                                                 const float* __restrict__ bias,
                                                 void* __restrict__ Cv,
                                                 int M, int N, int K) {
  __shared__ u16 lA[128 * 32];
  __shared__ u16 lB[128 * 32];
  const int tid = threadIdx.x;
  const int w = tid >> 6, l = tid & 63;
  const int wr = w >> 1, wc = w & 1;
  const int lr = l & 15, lg = l >> 4;
  const int tm = blockIdx.y * 128, tn = blockIdx.x * 128;
  const int Rr = l >> 2, Pp = l & 3;

  f32x4 acc[4][4];
#pragma unroll
  for (int m = 0; m < 4; m++)
#pragma unroll
    for (int n = 0; n < 4; n++) acc[m][n] = {0.f, 0.f, 0.f, 0.f};

  for (int k0 = 0; k0 < K; k0 += 32) {
#pragma unroll
    for (int i = 0; i < 2; i++) {
      int R = (i * 4 + w) * 16 + Rr;
      int cg = Pp ^ (R & 3);
      gload16(&lA[(i * 4 + w) * 512], &A[(long)(tm + R) * K + k0 + cg * 8]);
    }
#pragma unroll
    for (int i = 0; i < 2; i++) {
      int R = (i * 4 + w) * 16 + Rr;
      int cg = Pp ^ (R & 3);
      gload16(&lB[(i * 4 + w) * 512], &Bt[(long)(tn + R) * K + k0 + cg * 8]);
    }
    __syncthreads();
    bf16x8 af[4], bfr[4];
#pragma unroll
    for (int m = 0; m < 4; m++) {
      int r = wr * 64 + m * 16 + lr;
      af[m] = *(const bf16x8*)&lA[r * 32 + ((lg ^ (r & 3)) << 3)];
    }
#pragma unroll
    for (int n = 0; n < 4; n++) {
      int r = wc * 64 + n * 16 + lr;
      bfr[n] = *(const bf16x8*)&lB[r * 32 + ((lg ^ (r & 3)) << 3)];
    }
#pragma unroll
    for (int m = 0; m < 4; m++)
#pragma unroll
      for (int n = 0; n < 4; n++) acc[m][n] = mfma16(af[m], bfr[n], acc[m][n]);
    __syncthreads();
  }

#pragma unroll
  for (int n = 0; n < 4; n++) {
    int col = tn + wc * 64 + n * 16 + lr;
    float bv = bias[col];
#pragma unroll
    for (int m = 0; m < 4; m++) {
      int row0 = tm + wr * 64 + m * 16 + lg * 4;
#pragma unroll
      for (int j = 0; j < 4; j++) {
        float v = acc[m][n][j] + bv;
        if constexpr (BF16OUT)
          ((u16*)Cv)[(long)(row0 + j) * N + col] = f2bf(v);
        else
          ((float*)Cv)[(long)(row0 + j) * N + col] = v;
      }
    }
  }
}

// ------------- causal flash attention -------------
// grid (bh=32, qt=16) -> linear id qt*32+bh, XCD = bh%8: each XCD serves 4 heads
// (4 MB K/V working set == its L2). 256 thr = 4 waves, each wave owns 32 q-rows.
// KV tiles of 64, double-buffered LDS with global_load_lds prefetch of tile t+1
// issued before compute of tile t (one __syncthreads per tile).
__global__ __launch_bounds__(256) void k_attn(const u16* __restrict__ qkv,
                                              const u16* __restrict__ vt,
                                              const float* __restrict__ amask,
                                              u16* __restrict__ ctx) {
  __shared__ u16 lK[2][64 * 128];    // [key][d], chunk^(key&7) swizzle
  __shared__ u16 lV[2][128 * 64];    // [d][key], chunk^(d&7) swizzle
  __shared__ u16 lP[4][32 * 64];     // per-wave [qrow][key], chunk^(row&7) swizzle
  const int bh = blockIdx.x, b = bh >> 4, h = bh & 15;
  const int qt = blockIdx.y;
  const int tid = threadIdx.x, w = tid >> 6, l = tid & 63;
  const int lr = l & 15, lg = l >> 4;
  const int qrow0 = qt * 128 + w * 32;

  // Q fragments held in registers (direct global loads, 16B aligned)
  bf16x8 qf[2][4];
#pragma unroll
  for (int m = 0; m < 2; m++)
#pragma unroll
    for (int ks = 0; ks < 4; ks++)
      qf[m][ks] = *(const bf16x8*)&qkv[(long)(b * S_ + qrow0 + m * 16 + lr) * 6144 +
                                       h * 384 + ks * 32 + lg * 8];

  f32x4 accO[2][8];
#pragma unroll
  for (int m = 0; m < 2; m++)
#pragma unroll
    for (int n = 0; n < 8; n++) accO[m][n] = {0.f, 0.f, 0.f, 0.f};
  float mrun[2][4], lrun[2][4];
#pragma unroll
  for (int m = 0; m < 2; m++)
#pragma unroll
    for (int j = 0; j < 4; j++) { mrun[m][j] = -3.0e38f; lrun[m][j] = 0.f; }

  const int ntiles = 2 * qt + 2;

  // staging helper: K tile [64][128] + Vt tile [128][64] into buffer `buf`
  auto stage = [&](int buf, int t) {
#pragma unroll
    for (int i = 0; i < 4; i++) {
      int base = i * 256 + w * 64;             // wave-uniform chunk base
      int f = base + l;
      int r = f >> 4, cg = (f & 15) ^ (r & 7);
      gload16(&lK[buf][base * 8],
              &qkv[(long)(b * S_ + t * 64 + r) * 6144 + h * 384 + 128 + cg * 8]);
    }
#pragma unroll
    for (int i = 0; i < 4; i++) {
      int base = i * 256 + w * 64;
      int f = base + l;
      int r = f >> 3, cg = (f & 7) ^ (r & 7);
      gload16(&lV[buf][base * 8], &vt[((long)bh * HD_ + r) * S_ + t * 64 + cg * 8]);
    }
  };

  stage(0, 0);
  __syncthreads();

  for (int t = 0; t < ntiles; ++t) {
    const int cur = t & 1;
    if (t + 1 < ntiles) stage(cur ^ 1, t + 1);   // prefetch next tile (overlaps compute)

    const bool active = (t * 64 <= qrow0 + 31);
    if (active) {
      // QK^T
      f32x4 accS[2][4];
#pragma unroll
      for (int m = 0; m < 2; m++)
#pragma unroll
        for (int n = 0; n < 4; n++) accS[m][n] = {0.f, 0.f, 0.f, 0.f};
      __builtin_amdgcn_s_setprio(1);
#pragma unroll
      for (int ks = 0; ks < 4; ks++) {
        bf16x8 kf[4];
#pragma unroll
        for (int n = 0; n < 4; n++) {
          int key = n * 16 + lr;
          kf[n] = *(const bf16x8*)&lK[cur][key * 128 + (((ks * 4 + lg) ^ (key & 7)) << 3)];
        }
#pragma unroll
        for (int m = 0; m < 2; m++)
#pragma unroll
          for (int n = 0; n < 4; n++) accS[m][n] = mfma16(qf[m][ks], kf[n], accS[m][n]);
      }
      __builtin_amdgcn_s_setprio(0);
      float am[4];
#pragma unroll
      for (int n = 0; n < 4; n++) am[n] = amask[b * S_ + t * 64 + n * 16 + lr];
      const bool needmask = (t * 64 + 63 > qrow0);
      // online softmax per owned row (m,j); 4 rows in parallel across lg groups
#pragma unroll
      for (int m = 0; m < 2; m++) {
#pragma unroll
        for (int j = 0; j < 4; j++) {
          const int row = qrow0 + m * 16 + lg * 4 + j;
          const int prow = m * 16 + lg * 4 + j;
          float v[4];
#pragma unroll
          for (int n = 0; n < 4; n++) {
            v[n] = accS[m][n][j] * SCALE_ + am[n];
            if (needmask && (t * 64 + n * 16 + lr) > row) v[n] = -1e30f;
          }
          float rmax = fmaxf(fmaxf(v[0], v[1]), fmaxf(v[2], v[3]));
#pragma unroll
          for (int o = 1; o < 16; o <<= 1) rmax = fmaxf(rmax, __shfl_xor(rmax, o));
          const float mnew = fmaxf(mrun[m][j], rmax);
          const float corr = __expf(mrun[m][j] - mnew);
          float ls = 0.f;
#pragma unroll
          for (int n = 0; n < 4; n++) {
            float p = __expf(v[n] - mnew);
            ls += p;
            int pcol = n * 16 + lr;
            lP[w][prow * 64 + ((((pcol >> 3) ^ (prow & 7)) << 3) | (pcol & 7))] = f2bf(p);
          }
#pragma unroll
          for (int o = 1; o < 16; o <<= 1) ls += __shfl_xor(ls, o);
          lrun[m][j] = lrun[m][j] * corr + ls;
          mrun[m][j] = mnew;
#pragma unroll
          for (int n = 0; n < 8; n++) accO[m][n][j] *= corr;
        }
      }
      // PV: O += P * V   (A = P from wave-private LDS, B^T = Vt)
      __builtin_amdgcn_s_setprio(1);
#pragma unroll
      for (int ks = 0; ks < 2; ks++) {
        bf16x8 pa[2];
#pragma unroll
        for (int m = 0; m < 2; m++) {
          int r = m * 16 + lr;
          pa[m] = *(const bf16x8*)&lP[w][r * 64 + (((ks * 4 + lg) ^ (r & 7)) << 3)];
        }
#pragma unroll
        for (int n = 0; n < 8; n++) {
          int d = n * 16 + lr;
          bf16x8 vb = *(const bf16x8*)&lV[cur][d * 64 + (((ks * 4 + lg) ^ (d & 7)) << 3)];
#pragma unroll
          for (int m = 0; m < 2; m++) accO[m][n] = mfma16(pa[m], vb, accO[m][n]);
        }
      }
      __builtin_amdgcn_s_setprio(0);
    }
    __syncthreads();   // drains prefetch vmcnt (overlapped with compute) + LDS reads
  }

  // epilogue: O /= l, write ctx[b,s, h*128 + d] bf16
#pragma unroll
  for (int m = 0; m < 2; m++) {
#pragma unroll
    for (int j = 0; j < 4; j++) {
      float inv = 1.0f / lrun[m][j];
      int srow = qrow0 + m * 16 + lg * 4 + j;
#pragma unroll
      for (int n = 0; n < 8; n++)
        ctx[(long)(b * S_ + srow) * D_ + h * HD_ + n * 16 + lr] = f2bf(accO[m][n][j] * inv);
    }
  }
}

extern "C" void kernel_launch(void* const* d_in, const int* in_sizes, int n_in,
                              void* d_out, int out_size, void* d_ws, size_t ws_size,
                              hipStream_t stream) {
  const float* x  = (const float*)d_in[0];
  const float* am = (const float*)d_in[1];
  const float* wq = (const float*)d_in[2];
  const float* bq = (const float*)d_in[3];
  const float* wd = (const float*)d_in[4];
  const float* bd = (const float*)d_in[5];
  float* out = (float*)d_out;
  char* ws = (char*)d_ws;

  // workspace layout (92.3 MB peak, overlaid):
  u16* xb   = (u16*)(ws);                          // [4096][2048] bf16, 16 MB
  u16* wqT  = (u16*)(ws + (size_t)16777216);       // [6144][2048] bf16, 24 MB
  u16* qkvb = (u16*)(ws + (size_t)41943040);       // [4096][6144] bf16, 48 MB
  u16* vtb  = (u16*)(ws + (size_t)16777216);       // [32][128][2048] bf16 (reuses wqT)
  u16* wdT  = (u16*)(ws + (size_t)33554432);       // [2048][2048] bf16 (reuses wqT tail)
  u16* ctxb = (u16*)(ws);                          // [4096][2048] bf16 (reuses xb)

  k_cast_bf16<<<8192, 256, 0, stream>>>(x, xb, 2097152);
  k_transpose_cast<<<dim3(192, 64), dim3(32, 8), 0, stream>>>(wq, wqT, 2048, 6144);
  k_gemm_bt<true><<<dim3(48, 32), 256, 0, stream>>>(xb, wqT, bq, (void*)qkvb, 4096, 6144, 2048);
  k_extract_vt<<<dim3(4, 64, 32), dim3(32, 8), 0, stream>>>(qkvb, vtb);
  k_transpose_cast<<<dim3(64, 64), dim3(32, 8), 0, stream>>>(wd, wdT, 2048, 2048);
  k_attn<<<dim3(32, 16), 256, 0, stream>>>(qkvb, vtb, am, ctxb);
  k_gemm_bt<false><<<dim3(16, 32), 256, 0, stream>>>(ctxb, wdT, bd, (void*)out, 4096, 2048, 2048);
}